// Round 14
// baseline (270.450 us; speedup 1.0000x reference)
//
#include <hip/hip_runtime.h>

#define N_NODES 20000
#define N_EDGES 320000
#define NBATCH  128

typedef __attribute__((ext_vector_type(8))) short s8v;     // 8 bf16 (4 VGPRs)
typedef __attribute__((ext_vector_type(4))) float f32x4;
typedef __attribute__((ext_vector_type(4))) int i32x4;

__device__ __forceinline__ float lrelu(float v) { return v > 0.f ? v : 0.2f * v; }
__device__ __forceinline__ float rdlane(float v, int l) {
    return __int_as_float(__builtin_amdgcn_readlane(__float_as_int(v), l));
}
__device__ __forceinline__ unsigned short bf16_rne(float f) {
    unsigned u = __float_as_uint(f);
    unsigned r = u + 0x7FFF + ((u >> 16) & 1);
    return (unsigned short)(r >> 16);
}

// ---------------------------------------------------------------- setup: vsd + segst + zero deg + bf16-split weights
__global__ void k_small(const float* __restrict__ Wg, const float* __restrict__ Wh,
                        const float* __restrict__ att_s, const float* __restrict__ att_d,
                        float* __restrict__ vsd,
                        const int* __restrict__ batch, int* __restrict__ segst,
                        int* __restrict__ deg,
                        unsigned short* __restrict__ wgt_hi, unsigned short* __restrict__ wgt_lo,
                        unsigned short* __restrict__ wht_hi, unsigned short* __restrict__ wht_lo,
                        int n, int b) {
    int tid = threadIdx.x;
    int gid = blockIdx.x * 256 + tid;
    if (gid < n) deg[gid] = 0;
    if (blockIdx.x < 2) {
        int t = blockIdx.x * 256 + tid;   // 0..511
        int k = t >> 3, h = t & 7;
        const float* wrow = Wg + (size_t)k * 512 + h * 64;
        float s1 = 0.f, s2 = 0.f;
        #pragma unroll 8
        for (int c = 0; c < 64; c++) {
            float w = wrow[c];
            s1 += w * att_s[h * 64 + c];
            s2 += w * att_d[h * 64 + c];
        }
        vsd[k * 16 + h] = s1;
        vsd[k * 16 + 8 + h] = s2;
    } else if (blockIdx.x == 2) {
        if (tid > b) return;
        int lo = 0, hi = n;
        while (lo < hi) { int mid = (lo + hi) >> 1; if (batch[mid] < tid) lo = mid + 1; else hi = mid; }
        segst[tid] = lo;
    } else {
        int wi = (blockIdx.x - 3) * 256 + tid;   // 0..65535
        int sel = wi >> 15;                      // 0: Wg, 1: Wh
        int r = wi & 32767;
        int h = r >> 12, nn = (r >> 6) & 63, k = r & 63;
        float val = (sel == 0) ? Wg[(size_t)k * 512 + h * 64 + nn]
                               : Wh[(size_t)(h * 64 + k) * 64 + nn];
        unsigned short hi = bf16_rne(val);
        float hf = __uint_as_float((unsigned)hi << 16);
        unsigned short lo = bf16_rne(val - hf);
        int o = h * 4096 + nn * 64 + k;
        if (sel == 0) { wgt_hi[o] = hi; wgt_lo[o] = lo; }
        else          { wht_hi[o] = hi; wht_lo[o] = lo; }
    }
}

// ---------------------------------------------------------------- h0 = relu(x@W0+b0) + edge degree count
__global__ void k_h0c(const float* __restrict__ x, const float* __restrict__ W0,
                      const float* __restrict__ b0, float* __restrict__ h0,
                      const int* __restrict__ edst, int* __restrict__ deg, int n) {
    __shared__ float ws[25 * 64];
    __shared__ float bs[64];
    __shared__ float xs[100];
    int t = threadIdx.x;
    if (t < 64) {
        int e = blockIdx.x * 64 + t;
        atomicAdd(&deg[edst[e]], 1);
    }
    for (int i = t; i < 25 * 64; i += 256) ws[i] = W0[i];
    if (t < 64) bs[t] = b0[t];
    int nb = blockIdx.x * 4;
    if (t < 100 && nb * 25 + t < n * 25) xs[t] = x[(size_t)nb * 25 + t];
    __syncthreads();
    int node = nb + (t >> 6);
    int c = t & 63;
    if (node >= n) return;
    float s = bs[c];
    const float* xr = xs + (t >> 6) * 25;
    #pragma unroll
    for (int k = 0; k < 25; k++) s += xr[k] * ws[k * 64 + c];
    h0[(size_t)node * 64 + c] = fmaxf(s, 0.f);
}

// ---------------------------------------------------------------- [a_s|a_d] = h0 @ vsd  +  local scan (blocks >= nasd)
__global__ __launch_bounds__(256) void k_asd_scan(const float* __restrict__ h0,
                                                  const float* __restrict__ vsd,
                                                  float* __restrict__ a_s, float* __restrict__ a_d,
                                                  const int* __restrict__ deg,
                                                  int* __restrict__ tmp, int* __restrict__ bsum,
                                                  int nasd, int n) {
    __shared__ float hs[16][65];
    __shared__ float vl[64 * 16];
    __shared__ int wsum[4];
    int tid = threadIdx.x;
    if (blockIdx.x >= nasd) {
        int s = blockIdx.x - nasd;
        int i = s * 256 + tid;
        int lane = tid & 63, w = tid >> 6;
        int v = (i < n) ? deg[i] + 1 : 0;   // +1 self loop
        int x = v;
        #pragma unroll
        for (int off = 1; off < 64; off <<= 1) {
            int t2 = __shfl_up(x, off);
            if (lane >= off) x += t2;
        }
        if (lane == 63) wsum[w] = x;
        __syncthreads();
        int pre = 0;
        #pragma unroll
        for (int j = 0; j < 4; j++) if (j < w) pre += wsum[j];
        if (i < n) tmp[i] = pre + x - v;
        if (tid == 255) bsum[s] = pre + x;
        return;
    }
    int rbase = blockIdx.x * 16;
    {
        int row = tid / 16, c4 = (tid % 16) * 4;
        float4 hv = *(const float4*)(h0 + (size_t)(rbase + row) * 64 + c4);
        hs[row][c4] = hv.x; hs[row][c4 + 1] = hv.y; hs[row][c4 + 2] = hv.z; hs[row][c4 + 3] = hv.w;
    }
    #pragma unroll
    for (int j = 0; j < 4; j++) vl[tid + j * 256] = vsd[tid + j * 256];
    __syncthreads();
    int nl = tid / 16, o = tid % 16;
    float acc = 0.f;
    #pragma unroll 16
    for (int k = 0; k < 64; k++) acc += hs[nl][k] * vl[k * 16 + o];
    int node = rbase + nl;
    if (o < 8) a_s[node * 8 + o] = acc;
    else       a_d[node * 8 + (o - 8)] = acc;
}

// ---------------------------------------------------------------- scan2: global offsets + self loop
__global__ void k_scan2(const int* __restrict__ tmp, const int* __restrict__ bsum,
                        int* __restrict__ offs, int* __restrict__ adj,
                        int* __restrict__ cursor, int n, int nblk) {
    int i = blockIdx.x * 256 + threadIdx.x;
    if (i > n) return;
    int b = i >> 8;
    int pre = 0;
    for (int j = 0; j < b; j++) pre += bsum[j];
    if (i == n) {
        int tot = pre;
        for (int j = b; j < nblk; j++) tot += bsum[j];
        offs[n] = tot;
        return;
    }
    int o = pre + tmp[i];
    offs[i] = o;
    adj[o] = i;          // self loop first
    cursor[i] = o + 1;
}

// ---------------------------------------------------------------- fill edges (adj only)
__global__ void k_fill_edge(const int* __restrict__ src, const int* __restrict__ dst,
                            int* __restrict__ cursor, int* __restrict__ adj, int e) {
    int i = blockIdx.x * 256 + threadIdx.x;
    if (i >= e) return;
    int p = atomicAdd(&cursor[dst[i]], 1);
    adj[p] = src[i];
}

// ---------------------------------------------------------------- GAT: softmax + aggregate h0 (1 wave/node)
__global__ __launch_bounds__(256) void k_gat6(const int* __restrict__ offs, const int* __restrict__ adj,
                                              const float* __restrict__ a_s, const float* __restrict__ a_d,
                                              const float* __restrict__ h0,
                                              float* __restrict__ agg_pre, int n) {
    int lane = threadIdx.x & 63;
    int node = blockIdx.x * 4 + (threadIdx.x >> 6);
    if (node >= n) return;
    int beg = offs[node], end = offs[node + 1];
    int g = lane >> 3, h = lane & 7;
    float ad = a_d[node * 8 + h];

    float m = -1e30f, s = 0.f;
    for (int i = beg + g; i < end; i += 8) {
        int src = adj[i];
        float e = lrelu(a_s[src * 8 + h] + ad);
        if (e > m) { s = s * __expf(m - e) + 1.f; m = e; }
        else       { s += __expf(e - m); }
    }
    #pragma unroll
    for (int off = 8; off < 64; off <<= 1) {
        float mo = __shfl_xor(m, off), so = __shfl_xor(s, off);
        float mn = fmaxf(m, mo);
        s = s * __expf(m - mn) + so * __expf(mo - mn);
        m = mn;
    }
    float rcp = 1.f / s;

    float acc[8] = {0.f, 0.f, 0.f, 0.f, 0.f, 0.f, 0.f, 0.f};
    for (int sbase = beg; sbase < end; sbase += 64) {
        int scnt = end - sbase; if (scnt > 64) scnt = 64;
        int srcv = 0;
        if (lane < scnt) srcv = adj[sbase + lane];
        float al[8];
        #pragma unroll
        for (int j = 0; j < 8; j++) {
            int q = j * 8 + g;
            float alv = 0.f;
            if (q < scnt) {
                int sq = __shfl(srcv, q);
                float e = lrelu(a_s[sq * 8 + h] + ad);
                alv = __expf(e - m) * rcp;
            }
            al[j] = alv;
        }
        #pragma unroll
        for (int j = 0; j < 8; j += 2) {
            int qb0 = j * 8, qb1 = (j + 1) * 8;
            if (qb0 >= scnt) break;
            bool has1 = qb1 < scnt;
            int sg0[8], sg1[8];
            float xv0[8], xv1[8];
            #pragma unroll
            for (int g2 = 0; g2 < 8; g2++) sg0[g2] = __builtin_amdgcn_readlane(srcv, qb0 + g2);
            #pragma unroll
            for (int g2 = 0; g2 < 8; g2++) sg1[g2] = __builtin_amdgcn_readlane(srcv, qb1 + g2);
            #pragma unroll
            for (int g2 = 0; g2 < 8; g2++) xv0[g2] = h0[(size_t)sg0[g2] * 64 + lane];
            if (has1) {
                #pragma unroll
                for (int g2 = 0; g2 < 8; g2++) xv1[g2] = h0[(size_t)sg1[g2] * 64 + lane];
            }
            #pragma unroll
            for (int g2 = 0; g2 < 8; g2++) {
                #pragma unroll
                for (int h2 = 0; h2 < 8; h2++)
                    acc[h2] += rdlane(al[j], g2 * 8 + h2) * xv0[g2];
            }
            if (has1) {
                #pragma unroll
                for (int g2 = 0; g2 < 8; g2++) {
                    #pragma unroll
                    for (int h2 = 0; h2 < 8; h2++)
                        acc[h2] += rdlane(al[j + 1], g2 * 8 + h2) * xv1[g2];
                }
            }
        }
    }
    #pragma unroll
    for (int h2 = 0; h2 < 8; h2++)
        agg_pre[(size_t)node * 512 + h2 * 64 + lane] = acc[h2];
}

// ---------------------------------------------------------------- MFMA split-bf16 fused double GEMM -> partials
// 4 waves/block; wave = 16 rows; head pair = blockIdx.y. fp32-faithful hi/lo bf16 split (3 MFMA terms).
__global__ __launch_bounds__(256) void k_fmma(const float* __restrict__ agg_pre,
                                              const unsigned short* __restrict__ wgt_hi,
                                              const unsigned short* __restrict__ wgt_lo,
                                              const unsigned short* __restrict__ wht_hi,
                                              const unsigned short* __restrict__ wht_lo,
                                              const float* __restrict__ bg,
                                              float* __restrict__ part, int M) {
    __shared__ unsigned C1[4][16 * 68];   // per-wave slab: packed (hi | lo<<16) bf16 of relu(A@Wg+bg)
    int tid = threadIdx.x;
    int lane = tid & 63, wv = tid >> 6;
    int m = lane & 15, quad = lane >> 4;
    int r0 = blockIdx.x * 64 + wv * 16;
    int pair = blockIdx.y;
    unsigned* C1w = C1[wv];
    f32x4 accO[4];
    #pragma unroll
    for (int i = 0; i < 4; i++) accO[i] = (f32x4){0.f, 0.f, 0.f, 0.f};

    #pragma unroll
    for (int hh = 0; hh < 2; hh++) {
        int h = pair * 2 + hh;
        // A frags from agg_pre (fp32 -> hi/lo bf16); A[m=lane&15][k=quad*8+j]
        s8v ahi[2], alo[2];
        #pragma unroll
        for (int ks = 0; ks < 2; ks++) {
            float av[8] = {0.f, 0.f, 0.f, 0.f, 0.f, 0.f, 0.f, 0.f};
            if (r0 + m < M) {
                const float* ap = agg_pre + (size_t)(r0 + m) * 512 + h * 64 + ks * 32 + quad * 8;
                *(float4*)&av[0] = *(const float4*)ap;
                *(float4*)&av[4] = *(const float4*)(ap + 4);
            }
            #pragma unroll
            for (int j = 0; j < 8; j++) {
                unsigned short hi = bf16_rne(av[j]);
                float hf = __uint_as_float((unsigned)hi << 16);
                unsigned short lo = bf16_rne(av[j] - hf);
                ahi[ks][j] = (short)hi;
                alo[ks][j] = (short)lo;
            }
        }
        // GEMM1: C1 = relu(A @ Wg_h + bg)
        #pragma unroll
        for (int tn = 0; tn < 4; tn++) {
            f32x4 acc = (f32x4){0.f, 0.f, 0.f, 0.f};
            #pragma unroll
            for (int ks = 0; ks < 2; ks++) {
                const unsigned short* bp = wgt_hi + h * 4096 + (tn * 16 + m) * 64 + ks * 32 + quad * 8;
                const unsigned short* bl = wgt_lo + h * 4096 + (tn * 16 + m) * 64 + ks * 32 + quad * 8;
                s8v bhf = *(const s8v*)bp;
                s8v blf = *(const s8v*)bl;
                acc = __builtin_amdgcn_mfma_f32_16x16x32_bf16(alo[ks], bhf, acc, 0, 0, 0);
                acc = __builtin_amdgcn_mfma_f32_16x16x32_bf16(ahi[ks], blf, acc, 0, 0, 0);
                acc = __builtin_amdgcn_mfma_f32_16x16x32_bf16(ahi[ks], bhf, acc, 0, 0, 0);
            }
            float bgv = bg[h * 64 + tn * 16 + m];
            #pragma unroll
            for (int r = 0; r < 4; r++) {
                float v = fmaxf(acc[r] + bgv, 0.f);
                unsigned short hi = bf16_rne(v);
                float hf = __uint_as_float((unsigned)hi << 16);
                unsigned short lo = bf16_rne(v - hf);
                C1w[(quad * 4 + r) * 68 + tn * 16 + m] = (unsigned)hi | ((unsigned)lo << 16);
            }
        }
        __syncthreads();   // C1 writes -> reads (waves symmetric)
        // GEMM2: accO += C1 @ Wh_h
        s8v a2h[2], a2l[2];
        #pragma unroll
        for (int ks = 0; ks < 2; ks++) {
            const unsigned* cp = &C1w[m * 68 + ks * 32 + quad * 8];
            unsigned uu[8];
            *(i32x4*)&uu[0] = *(const i32x4*)cp;
            *(i32x4*)&uu[4] = *(const i32x4*)(cp + 4);
            #pragma unroll
            for (int j = 0; j < 8; j++) {
                a2h[ks][j] = (short)(uu[j] & 0xFFFFu);
                a2l[ks][j] = (short)(uu[j] >> 16);
            }
        }
        #pragma unroll
        for (int tn = 0; tn < 4; tn++) {
            #pragma unroll
            for (int ks = 0; ks < 2; ks++) {
                const unsigned short* bp = wht_hi + h * 4096 + (tn * 16 + m) * 64 + ks * 32 + quad * 8;
                const unsigned short* bl = wht_lo + h * 4096 + (tn * 16 + m) * 64 + ks * 32 + quad * 8;
                s8v bhf = *(const s8v*)bp;
                s8v blf = *(const s8v*)bl;
                accO[tn] = __builtin_amdgcn_mfma_f32_16x16x32_bf16(a2l[ks], bhf, accO[tn], 0, 0, 0);
                accO[tn] = __builtin_amdgcn_mfma_f32_16x16x32_bf16(a2h[ks], blf, accO[tn], 0, 0, 0);
                accO[tn] = __builtin_amdgcn_mfma_f32_16x16x32_bf16(a2h[ks], bhf, accO[tn], 0, 0, 0);
            }
        }
        __syncthreads();   // before next head overwrites C1
    }
    // write partials: C/D layout col=lane&15, row=quad*4+reg
    float* Cb = part + (size_t)pair * M * 64;
    #pragma unroll
    for (int tn = 0; tn < 4; tn++) {
        #pragma unroll
        for (int r = 0; r < 4; r++) {
            int row = r0 + quad * 4 + r;
            if (row < M) Cb[(size_t)row * 64 + tn * 16 + m] = accO[tn][r];
        }
    }
}

// ---------------------------------------------------------------- Set2Set (3 iters) + final MLP; sums 4 partials + bh + relu on load
#define SROWS 208
__global__ __launch_bounds__(256) void k_s2s(const float* __restrict__ part,
                                             const float* __restrict__ bh,
                                             const int* __restrict__ segst,
                                             const float* __restrict__ W_ih, const float* __restrict__ W_hh,
                                             const float* __restrict__ b_ih, const float* __restrict__ b_hh,
                                             const float* __restrict__ W1, const float* __restrict__ b1,
                                             const float* __restrict__ W2, const float* __restrict__ b2,
                                             float* __restrict__ out, int M) {
    int b = blockIdx.x, tid = threadIdx.x, lane = tid & 63, w = tid >> 6;
    __shared__ float sc[SROWS * 65];
    __shared__ float wlds[1024];
    __shared__ float hl[64], cl[64], rl_[64];
    __shared__ float red[4];
    __shared__ float gsh[256];
    int beg = segst[b], end = segst[b + 1];
    int nrows = end - beg;
    int ncache = nrows < SROWS ? nrows : SROWS;
    const size_t PS = (size_t)M * 64;
    for (int idx = tid; idx < ncache * 16; idx += 256) {
        int r = idx >> 4, q = idx & 15;
        const float* pb = part + (size_t)(beg + r) * 64 + q * 4;
        float4 v0 = *(const float4*)pb;
        float4 v1 = *(const float4*)(pb + PS);
        float4 v2 = *(const float4*)(pb + 2 * PS);
        float4 v3 = *(const float4*)(pb + 3 * PS);
        float4 bv = *(const float4*)(bh + q * 4);
        float* p = &sc[r * 65 + q * 4];
        p[0] = fmaxf(v0.x + v1.x + v2.x + v3.x + bv.x, 0.f);
        p[1] = fmaxf(v0.y + v1.y + v2.y + v3.y + bv.y, 0.f);
        p[2] = fmaxf(v0.z + v1.z + v2.z + v3.z + bv.z, 0.f);
        p[3] = fmaxf(v0.w + v1.w + v2.w + v3.w + bv.w, 0.f);
    }
    if (tid < 64) { hl[tid] = 0.f; cl[tid] = 0.f; rl_[tid] = 0.f; }
    __syncthreads();

    for (int it = 0; it < 3; it++) {
        {
            float acc = b_ih[tid] + b_hh[tid];
            const float* wi = W_ih + (size_t)tid * 128;
            const float* wh = W_hh + (size_t)tid * 64;
            #pragma unroll 8
            for (int k = 0; k < 64; k++) acc += hl[k] * (wi[k] + wh[k]) + rl_[k] * wi[64 + k];
            gsh[tid] = acc;
        }
        __syncthreads();
        if (tid < 64) {
            float ig = gsh[tid], fg = gsh[64 + tid], gg = gsh[128 + tid], og = gsh[192 + tid];
            float cc = cl[tid];
            float si = 1.f / (1.f + __expf(-ig));
            float sf = 1.f / (1.f + __expf(-fg));
            float so = 1.f / (1.f + __expf(-og));
            float cn = sf * cc + si * tanhf(gg);
            cl[tid] = cn;
            hl[tid] = so * tanhf(cn);
        }
        __syncthreads();
        float ev[4];
        int nr = 0;
        float mloc = -1e30f;
        for (int i = tid; i < nrows; i += 256) {
            float d = 0.f;
            if (i < SROWS) {
                const float* rp = &sc[i * 65];
                #pragma unroll 16
                for (int j = 0; j < 64; j++) d += rp[j] * hl[j];
            } else {
                const float* pb = part + (size_t)(beg + i) * 64;
                for (int j = 0; j < 64; j++) {
                    float v = pb[j] + pb[PS + j] + pb[2 * PS + j] + pb[3 * PS + j] + bh[j];
                    d += fmaxf(v, 0.f) * hl[j];
                }
            }
            ev[nr++] = d;
            mloc = fmaxf(mloc, d);
        }
        #pragma unroll
        for (int off = 1; off < 64; off <<= 1) mloc = fmaxf(mloc, __shfl_xor(mloc, off));
        if (lane == 0) red[w] = mloc;
        __syncthreads();
        float m = fmaxf(fmaxf(red[0], red[1]), fmaxf(red[2], red[3]));
        __syncthreads();
        float sloc = 0.f;
        nr = 0;
        for (int i = tid; i < nrows; i += 256) {
            float wv = __expf(ev[nr++] - m);
            if (i < 1024) wlds[i] = wv;
            sloc += wv;
        }
        #pragma unroll
        for (int off = 1; off < 64; off <<= 1) sloc += __shfl_xor(sloc, off);
        if (lane == 0) red[w] = sloc;
        __syncthreads();
        float sv = red[0] + red[1] + red[2] + red[3];
        float inv = sv > 0.f ? 1.f / sv : 0.f;
        float acc = 0.f;
        for (int i = w; i < nrows; i += 4) {
            float v;
            if (i < SROWS) v = sc[i * 65 + lane];
            else {
                const float* pb = part + (size_t)(beg + i) * 64 + lane;
                v = fmaxf(pb[0] + pb[PS] + pb[2 * PS] + pb[3 * PS] + bh[lane], 0.f);
            }
            acc += wlds[i] * v;
        }
        gsh[w * 64 + lane] = acc;
        __syncthreads();
        if (tid < 64)
            rl_[tid] = (gsh[tid] + gsh[64 + tid] + gsh[128 + tid] + gsh[192 + tid]) * inv;
        __syncthreads();
    }
    if (tid < 64) {
        float t = b1[tid];
        #pragma unroll 8
        for (int k = 0; k < 64; k++)
            t += hl[k] * W1[(size_t)k * 64 + tid] + rl_[k] * W1[(size_t)(64 + k) * 64 + tid];
        t = fmaxf(t, 0.f) * W2[tid];
        #pragma unroll
        for (int off = 32; off > 0; off >>= 1) t += __shfl_xor(t, off);
        if (tid == 0) out[b] = t + b2[0];
    }
}

// ----------------------------------------------------------------
extern "C" void kernel_launch(void* const* d_in, const int* in_sizes, int n_in,
                              void* d_out, int out_size, void* d_ws, size_t ws_size,
                              hipStream_t stream) {
    const float* x     = (const float*)d_in[0];
    const int*   ei    = (const int*)d_in[1];
    const int*   batch = (const int*)d_in[2];
    const float* W0    = (const float*)d_in[3];
    const float* b0    = (const float*)d_in[4];
    const float* Wg    = (const float*)d_in[5];
    const float* att_s = (const float*)d_in[6];
    const float* att_d = (const float*)d_in[7];
    const float* bg    = (const float*)d_in[8];
    const float* Wh    = (const float*)d_in[9];
    const float* bh    = (const float*)d_in[10];
    const float* W_ih  = (const float*)d_in[11];
    const float* W_hh  = (const float*)d_in[12];
    const float* b_ih  = (const float*)d_in[13];
    const float* b_hh  = (const float*)d_in[14];
    const float* W1    = (const float*)d_in[15];
    const float* b1    = (const float*)d_in[16];
    const float* W2    = (const float*)d_in[17];
    const float* b2    = (const float*)d_in[18];
    float* out = (float*)d_out;

    const int* esrc = ei;
    const int* edst = ei + N_EDGES;

    char* wsb = (char*)d_ws;
    size_t off = 0;
    auto alloc = [&](size_t bytes) {
        void* p = wsb + off;
        off = (off + bytes + 255) & ~(size_t)255;
        return p;
    };
    float* h0      = (float*)alloc((size_t)N_NODES * 64 * 4);
    float* agg_pre = (float*)alloc((size_t)N_NODES * 512 * 4);
    float* part    = (float*)alloc((size_t)4 * N_NODES * 64 * 4);
    float* a_s     = (float*)alloc((size_t)N_NODES * 8 * 4);
    float* a_d     = (float*)alloc((size_t)N_NODES * 8 * 4);
    float* vsd     = (float*)alloc(64 * 16 * 4);
    unsigned short* wgt_hi = (unsigned short*)alloc(32768 * 2);
    unsigned short* wgt_lo = (unsigned short*)alloc(32768 * 2);
    unsigned short* wht_hi = (unsigned short*)alloc(32768 * 2);
    unsigned short* wht_lo = (unsigned short*)alloc(32768 * 2);
    int*   deg     = (int*)alloc((size_t)N_NODES * 4);
    int*   tmp     = (int*)alloc((size_t)N_NODES * 4);
    int*   bsum    = (int*)alloc(128 * 4);
    int*   offs    = (int*)alloc((size_t)(N_NODES + 1) * 4);
    int*   cursor  = (int*)alloc((size_t)N_NODES * 4);
    int*   adj     = (int*)alloc((size_t)(N_EDGES + N_NODES) * 4);
    int*   segst   = (int*)alloc((size_t)(NBATCH + 1) * 4);

    const int nscan = (N_NODES + 255) / 256;    // 79
    const int nasd  = N_NODES / 16;             // 1250

    k_small<<<259, 256, 0, stream>>>(Wg, Wh, att_s, att_d, vsd, batch, segst, deg,
                                     wgt_hi, wgt_lo, wht_hi, wht_lo, N_NODES, NBATCH);
    k_h0c<<<N_NODES / 4, 256, 0, stream>>>(x, W0, b0, h0, edst, deg, N_NODES);
    k_asd_scan<<<nasd + nscan, 256, 0, stream>>>(h0, vsd, a_s, a_d, deg, tmp, bsum, nasd, N_NODES);

    k_scan2<<<(N_NODES + 256) / 256, 256, 0, stream>>>(tmp, bsum, offs, adj, cursor, N_NODES, nscan);
    k_fill_edge<<<(N_EDGES + 255) / 256, 256, 0, stream>>>(esrc, edst, cursor, adj, N_EDGES);

    k_gat6<<<(N_NODES + 3) / 4, 256, 0, stream>>>(offs, adj, a_s, a_d, h0, agg_pre, N_NODES);
    k_fmma<<<dim3((N_NODES + 63) / 64, 4), 256, 0, stream>>>(agg_pre, wgt_hi, wgt_lo, wht_hi, wht_lo,
                                                             bg, part, N_NODES);

    k_s2s<<<NBATCH, 256, 0, stream>>>(part, bh, segst, W_ih, W_hh, b_ih, b_hh, W1, b1, W2, b2, out, N_NODES);
}

// Round 15
// 263.370 us; speedup vs baseline: 1.0269x; 1.0269x over previous
//
#include <hip/hip_runtime.h>

#define N_NODES 20000
#define N_EDGES 320000
#define NBATCH  128

typedef __attribute__((ext_vector_type(8))) short s8v;     // 8 bf16 (4 VGPRs)
typedef __attribute__((ext_vector_type(4))) float f32x4;
typedef __attribute__((ext_vector_type(4))) int i32x4;

__device__ __forceinline__ float lrelu(float v) { return v > 0.f ? v : 0.2f * v; }
__device__ __forceinline__ float rdlane(float v, int l) {
    return __int_as_float(__builtin_amdgcn_readlane(__float_as_int(v), l));
}
__device__ __forceinline__ unsigned short bf16_rne(float f) {
    unsigned u = __float_as_uint(f);
    unsigned r = u + 0x7FFF + ((u >> 16) & 1);
    return (unsigned short)(r >> 16);
}

// ---------------------------------------------------------------- setup: vsd + segst + zero deg + bf16-split weights
__global__ void k_small(const float* __restrict__ Wg, const float* __restrict__ Wh,
                        const float* __restrict__ att_s, const float* __restrict__ att_d,
                        float* __restrict__ vsd,
                        const int* __restrict__ batch, int* __restrict__ segst,
                        int* __restrict__ deg,
                        unsigned short* __restrict__ wgt_hi, unsigned short* __restrict__ wgt_lo,
                        unsigned short* __restrict__ wht_hi, unsigned short* __restrict__ wht_lo,
                        int n, int b) {
    int tid = threadIdx.x;
    int gid = blockIdx.x * 256 + tid;
    if (gid < n) deg[gid] = 0;
    if (blockIdx.x < 2) {
        int t = blockIdx.x * 256 + tid;   // 0..511
        int k = t >> 3, h = t & 7;
        const float* wrow = Wg + (size_t)k * 512 + h * 64;
        float s1 = 0.f, s2 = 0.f;
        #pragma unroll 8
        for (int c = 0; c < 64; c++) {
            float w = wrow[c];
            s1 += w * att_s[h * 64 + c];
            s2 += w * att_d[h * 64 + c];
        }
        vsd[k * 16 + h] = s1;
        vsd[k * 16 + 8 + h] = s2;
    } else if (blockIdx.x == 2) {
        if (tid > b) return;
        int lo = 0, hi = n;
        while (lo < hi) { int mid = (lo + hi) >> 1; if (batch[mid] < tid) lo = mid + 1; else hi = mid; }
        segst[tid] = lo;
    } else {
        int wi = (blockIdx.x - 3) * 256 + tid;   // 0..65535
        int sel = wi >> 15;                      // 0: Wg, 1: Wh
        int r = wi & 32767;
        int h = r >> 12, nn = (r >> 6) & 63, k = r & 63;
        float val = (sel == 0) ? Wg[(size_t)k * 512 + h * 64 + nn]
                               : Wh[(size_t)(h * 64 + k) * 64 + nn];
        unsigned short hi = bf16_rne(val);
        float hf = __uint_as_float((unsigned)hi << 16);
        unsigned short lo = bf16_rne(val - hf);
        int o = h * 4096 + nn * 64 + k;
        if (sel == 0) { wgt_hi[o] = hi; wgt_lo[o] = lo; }
        else          { wht_hi[o] = hi; wht_lo[o] = lo; }
    }
}

// ---------------------------------------------------------------- h0 = relu(x@W0+b0) + edge degree count
__global__ void k_h0c(const float* __restrict__ x, const float* __restrict__ W0,
                      const float* __restrict__ b0, float* __restrict__ h0,
                      const int* __restrict__ edst, int* __restrict__ deg, int n) {
    __shared__ float ws[25 * 64];
    __shared__ float bs[64];
    __shared__ float xs[100];
    int t = threadIdx.x;
    if (t < 64) {
        int e = blockIdx.x * 64 + t;
        atomicAdd(&deg[edst[e]], 1);
    }
    for (int i = t; i < 25 * 64; i += 256) ws[i] = W0[i];
    if (t < 64) bs[t] = b0[t];
    int nb = blockIdx.x * 4;
    if (t < 100 && nb * 25 + t < n * 25) xs[t] = x[(size_t)nb * 25 + t];
    __syncthreads();
    int node = nb + (t >> 6);
    int c = t & 63;
    if (node >= n) return;
    float s = bs[c];
    const float* xr = xs + (t >> 6) * 25;
    #pragma unroll
    for (int k = 0; k < 25; k++) s += xr[k] * ws[k * 64 + c];
    h0[(size_t)node * 64 + c] = fmaxf(s, 0.f);
}

// ---------------------------------------------------------------- [a_s|a_d] = h0 @ vsd  +  local scan (blocks >= nasd)
__global__ __launch_bounds__(256) void k_asd_scan(const float* __restrict__ h0,
                                                  const float* __restrict__ vsd,
                                                  float* __restrict__ a_s, float* __restrict__ a_d,
                                                  const int* __restrict__ deg,
                                                  int* __restrict__ tmp, int* __restrict__ bsum,
                                                  int nasd, int n) {
    __shared__ float hs[16][65];
    __shared__ float vl[64 * 16];
    __shared__ int wsum[4];
    int tid = threadIdx.x;
    if (blockIdx.x >= nasd) {
        int s = blockIdx.x - nasd;
        int i = s * 256 + tid;
        int lane = tid & 63, w = tid >> 6;
        int v = (i < n) ? deg[i] + 1 : 0;   // +1 self loop
        int x = v;
        #pragma unroll
        for (int off = 1; off < 64; off <<= 1) {
            int t2 = __shfl_up(x, off);
            if (lane >= off) x += t2;
        }
        if (lane == 63) wsum[w] = x;
        __syncthreads();
        int pre = 0;
        #pragma unroll
        for (int j = 0; j < 4; j++) if (j < w) pre += wsum[j];
        if (i < n) tmp[i] = pre + x - v;
        if (tid == 255) bsum[s] = pre + x;
        return;
    }
    int rbase = blockIdx.x * 16;
    {
        int row = tid / 16, c4 = (tid % 16) * 4;
        float4 hv = *(const float4*)(h0 + (size_t)(rbase + row) * 64 + c4);
        hs[row][c4] = hv.x; hs[row][c4 + 1] = hv.y; hs[row][c4 + 2] = hv.z; hs[row][c4 + 3] = hv.w;
    }
    #pragma unroll
    for (int j = 0; j < 4; j++) vl[tid + j * 256] = vsd[tid + j * 256];
    __syncthreads();
    int nl = tid / 16, o = tid % 16;
    float acc = 0.f;
    #pragma unroll 16
    for (int k = 0; k < 64; k++) acc += hs[nl][k] * vl[k * 16 + o];
    int node = rbase + nl;
    if (o < 8) a_s[node * 8 + o] = acc;
    else       a_d[node * 8 + (o - 8)] = acc;
}

// ---------------------------------------------------------------- scan2: global offsets + self loop
__global__ void k_scan2(const int* __restrict__ tmp, const int* __restrict__ bsum,
                        int* __restrict__ offs, int* __restrict__ adj,
                        int* __restrict__ cursor, int n, int nblk) {
    int i = blockIdx.x * 256 + threadIdx.x;
    if (i > n) return;
    int b = i >> 8;
    int pre = 0;
    for (int j = 0; j < b; j++) pre += bsum[j];
    if (i == n) {
        int tot = pre;
        for (int j = b; j < nblk; j++) tot += bsum[j];
        offs[n] = tot;
        return;
    }
    int o = pre + tmp[i];
    offs[i] = o;
    adj[o] = i;          // self loop first
    cursor[i] = o + 1;
}

// ---------------------------------------------------------------- fill edges (adj only)
__global__ void k_fill_edge(const int* __restrict__ src, const int* __restrict__ dst,
                            int* __restrict__ cursor, int* __restrict__ adj, int e) {
    int i = blockIdx.x * 256 + threadIdx.x;
    if (i >= e) return;
    int p = atomicAdd(&cursor[dst[i]], 1);
    adj[p] = src[i];
}

// ---------------------------------------------------------------- FUSED: GAT aggregate (16 waves/16 nodes) + MFMA double-GEMM -> out2
#define ASTR 520   // staging row stride (floats); 520*4 B, 16B-aligned
__global__ __launch_bounds__(1024) void k_gatf(const int* __restrict__ offs, const int* __restrict__ adj,
                                               const float* __restrict__ a_s, const float* __restrict__ a_d,
                                               const float* __restrict__ h0,
                                               const unsigned short* __restrict__ wgt_hi,
                                               const unsigned short* __restrict__ wgt_lo,
                                               const unsigned short* __restrict__ wht_hi,
                                               const unsigned short* __restrict__ wht_lo,
                                               const float* __restrict__ bg, const float* __restrict__ bh,
                                               float* __restrict__ out2, int n) {
    __shared__ float stg[16 * ASTR];      // phase1: agg rows [16][512]; phase2 out: partials [8][16][64]
    __shared__ unsigned C1[8][16 * 68];   // per-head-wave slab: packed (hi|lo<<16) bf16
    int tid = threadIdx.x;
    int lane = tid & 63, wv = tid >> 6;
    int node = blockIdx.x * 16 + wv;

    // ---------------- phase 1: per-wave GAT aggregation (identical math to k_gat6)
    {
        int beg = offs[node], end = offs[node + 1];
        int g = lane >> 3, h = lane & 7;
        float ad = a_d[node * 8 + h];
        float m = -1e30f, s = 0.f;
        for (int i = beg + g; i < end; i += 8) {
            int src = adj[i];
            float e = lrelu(a_s[src * 8 + h] + ad);
            if (e > m) { s = s * __expf(m - e) + 1.f; m = e; }
            else       { s += __expf(e - m); }
        }
        #pragma unroll
        for (int off = 8; off < 64; off <<= 1) {
            float mo = __shfl_xor(m, off), so = __shfl_xor(s, off);
            float mn = fmaxf(m, mo);
            s = s * __expf(m - mn) + so * __expf(mo - mn);
            m = mn;
        }
        float rcp = 1.f / s;

        float acc[8] = {0.f, 0.f, 0.f, 0.f, 0.f, 0.f, 0.f, 0.f};
        for (int sbase = beg; sbase < end; sbase += 64) {
            int scnt = end - sbase; if (scnt > 64) scnt = 64;
            int srcv = 0;
            if (lane < scnt) srcv = adj[sbase + lane];
            float al[8];
            #pragma unroll
            for (int j = 0; j < 8; j++) {
                int q = j * 8 + g;
                float alv = 0.f;
                if (q < scnt) {
                    int sq = __shfl(srcv, q);
                    float e = lrelu(a_s[sq * 8 + h] + ad);
                    alv = __expf(e - m) * rcp;
                }
                al[j] = alv;
            }
            #pragma unroll
            for (int j = 0; j < 8; j += 2) {
                int qb0 = j * 8, qb1 = (j + 1) * 8;
                if (qb0 >= scnt) break;
                bool has1 = qb1 < scnt;
                int sg0[8], sg1[8];
                float xv0[8], xv1[8];
                #pragma unroll
                for (int g2 = 0; g2 < 8; g2++) sg0[g2] = __builtin_amdgcn_readlane(srcv, qb0 + g2);
                #pragma unroll
                for (int g2 = 0; g2 < 8; g2++) sg1[g2] = __builtin_amdgcn_readlane(srcv, qb1 + g2);
                #pragma unroll
                for (int g2 = 0; g2 < 8; g2++) xv0[g2] = h0[(size_t)sg0[g2] * 64 + lane];
                if (has1) {
                    #pragma unroll
                    for (int g2 = 0; g2 < 8; g2++) xv1[g2] = h0[(size_t)sg1[g2] * 64 + lane];
                }
                #pragma unroll
                for (int g2 = 0; g2 < 8; g2++) {
                    #pragma unroll
                    for (int h2 = 0; h2 < 8; h2++)
                        acc[h2] += rdlane(al[j], g2 * 8 + h2) * xv0[g2];
                }
                if (has1) {
                    #pragma unroll
                    for (int g2 = 0; g2 < 8; g2++) {
                        #pragma unroll
                        for (int h2 = 0; h2 < 8; h2++)
                            acc[h2] += rdlane(al[j + 1], g2 * 8 + h2) * xv1[g2];
                    }
                }
            }
        }
        // stage agg row wv: [wv][h2*64 + lane]
        #pragma unroll
        for (int h2 = 0; h2 < 8; h2++)
            stg[wv * ASTR + h2 * 64 + lane] = acc[h2];
    }
    __syncthreads();

    // ---------------- phase 2: waves 0..7 run head h = wv double-GEMM (16 rows)
    int m16 = lane & 15, quad = lane >> 4;
    f32x4 accO[4];
    #pragma unroll
    for (int i = 0; i < 4; i++) accO[i] = (f32x4){0.f, 0.f, 0.f, 0.f};
    if (wv < 8) {
        int h = wv;
        // A frags from staging (fp32 -> hi/lo bf16); A[m=lane&15][k=quad*8+j]
        s8v ahi[2], alo[2];
        #pragma unroll
        for (int ks = 0; ks < 2; ks++) {
            const float* ap = &stg[m16 * ASTR + h * 64 + ks * 32 + quad * 8];
            float av[8];
            *(float4*)&av[0] = *(const float4*)ap;
            *(float4*)&av[4] = *(const float4*)(ap + 4);
            #pragma unroll
            for (int j = 0; j < 8; j++) {
                unsigned short hi = bf16_rne(av[j]);
                float hf = __uint_as_float((unsigned)hi << 16);
                unsigned short lo = bf16_rne(av[j] - hf);
                ahi[ks][j] = (short)hi;
                alo[ks][j] = (short)lo;
            }
        }
        unsigned* C1w = C1[h];
        // GEMM1: C1 = relu(A @ Wg_h + bg)
        #pragma unroll
        for (int tn = 0; tn < 4; tn++) {
            f32x4 acc = (f32x4){0.f, 0.f, 0.f, 0.f};
            #pragma unroll
            for (int ks = 0; ks < 2; ks++) {
                const unsigned short* bp = wgt_hi + h * 4096 + (tn * 16 + m16) * 64 + ks * 32 + quad * 8;
                const unsigned short* bl = wgt_lo + h * 4096 + (tn * 16 + m16) * 64 + ks * 32 + quad * 8;
                s8v bhf = *(const s8v*)bp;
                s8v blf = *(const s8v*)bl;
                acc = __builtin_amdgcn_mfma_f32_16x16x32_bf16(alo[ks], bhf, acc, 0, 0, 0);
                acc = __builtin_amdgcn_mfma_f32_16x16x32_bf16(ahi[ks], blf, acc, 0, 0, 0);
                acc = __builtin_amdgcn_mfma_f32_16x16x32_bf16(ahi[ks], bhf, acc, 0, 0, 0);
            }
            float bgv = bg[h * 64 + tn * 16 + m16];
            #pragma unroll
            for (int r = 0; r < 4; r++) {
                float v = fmaxf(acc[r] + bgv, 0.f);
                unsigned short hi = bf16_rne(v);
                float hf = __uint_as_float((unsigned)hi << 16);
                unsigned short lo = bf16_rne(v - hf);
                C1w[(quad * 4 + r) * 68 + tn * 16 + m16] = (unsigned)hi | ((unsigned)lo << 16);
            }
        }
        // private-slab roundtrip: only lgkmcnt (compiler-inserted), no barrier
        s8v a2h[2], a2l[2];
        #pragma unroll
        for (int ks = 0; ks < 2; ks++) {
            const unsigned* cp = &C1w[m16 * 68 + ks * 32 + quad * 8];
            unsigned uu[8];
            *(i32x4*)&uu[0] = *(const i32x4*)cp;
            *(i32x4*)&uu[4] = *(const i32x4*)(cp + 4);
            #pragma unroll
            for (int j = 0; j < 8; j++) {
                a2h[ks][j] = (short)(uu[j] & 0xFFFFu);
                a2l[ks][j] = (short)(uu[j] >> 16);
            }
        }
        #pragma unroll
        for (int tn = 0; tn < 4; tn++) {
            #pragma unroll
            for (int ks = 0; ks < 2; ks++) {
                const unsigned short* bp = wht_hi + h * 4096 + (tn * 16 + m16) * 64 + ks * 32 + quad * 8;
                const unsigned short* bl = wht_lo + h * 4096 + (tn * 16 + m16) * 64 + ks * 32 + quad * 8;
                s8v bhf = *(const s8v*)bp;
                s8v blf = *(const s8v*)bl;
                accO[tn] = __builtin_amdgcn_mfma_f32_16x16x32_bf16(a2l[ks], bhf, accO[tn], 0, 0, 0);
                accO[tn] = __builtin_amdgcn_mfma_f32_16x16x32_bf16(a2h[ks], blf, accO[tn], 0, 0, 0);
                accO[tn] = __builtin_amdgcn_mfma_f32_16x16x32_bf16(a2h[ks], bhf, accO[tn], 0, 0, 0);
            }
        }
    }
    __syncthreads();   // all A-reads from stg done; safe to overwrite with partials
    if (wv < 8) {
        // write head partial to stg as [h][16][64]: C/D layout col=lane&15, row=quad*4+r
        float* Pw = &stg[wv * 1024];
        #pragma unroll
        for (int tn = 0; tn < 4; tn++) {
            #pragma unroll
            for (int r = 0; r < 4; r++)
                Pw[(quad * 4 + r) * 64 + tn * 16 + m16] = accO[tn][r];
        }
    }
    __syncthreads();

    // ---------------- phase 3: reduce 8 head-partials + bh + relu -> out2
    {
        int row = tid >> 6, col = tid & 63;   // 16 rows x 64 cols
        float s = stg[row * 64 + col];
        #pragma unroll
        for (int h2 = 1; h2 < 8; h2++) s += stg[h2 * 1024 + row * 64 + col];
        out2[(size_t)(blockIdx.x * 16 + row) * 64 + col] = fmaxf(s + bh[col], 0.f);
    }
}

// ---------------------------------------------------------------- Set2Set (3 iters) + final MLP (reads finished out2)
#define SROWS 208
__global__ __launch_bounds__(256) void k_s2s(const float* __restrict__ out2,
                                             const int* __restrict__ segst,
                                             const float* __restrict__ W_ih, const float* __restrict__ W_hh,
                                             const float* __restrict__ b_ih, const float* __restrict__ b_hh,
                                             const float* __restrict__ W1, const float* __restrict__ b1,
                                             const float* __restrict__ W2, const float* __restrict__ b2,
                                             float* __restrict__ out) {
    int b = blockIdx.x, tid = threadIdx.x, lane = tid & 63, w = tid >> 6;
    __shared__ float sc[SROWS * 65];
    __shared__ float wlds[1024];
    __shared__ float hl[64], cl[64], rl_[64];
    __shared__ float red[4];
    __shared__ float gsh[256];
    int beg = segst[b], end = segst[b + 1];
    int nrows = end - beg;
    int ncache = nrows < SROWS ? nrows : SROWS;
    for (int idx = tid; idx < ncache * 16; idx += 256) {
        int r = idx >> 4, q = idx & 15;
        float4 v = *(const float4*)(out2 + (size_t)(beg + r) * 64 + q * 4);
        float* p = &sc[r * 65 + q * 4];
        p[0] = v.x; p[1] = v.y; p[2] = v.z; p[3] = v.w;
    }
    if (tid < 64) { hl[tid] = 0.f; cl[tid] = 0.f; rl_[tid] = 0.f; }
    __syncthreads();

    for (int it = 0; it < 3; it++) {
        {
            float acc = b_ih[tid] + b_hh[tid];
            const float* wi = W_ih + (size_t)tid * 128;
            const float* wh = W_hh + (size_t)tid * 64;
            #pragma unroll 8
            for (int k = 0; k < 64; k++) acc += hl[k] * (wi[k] + wh[k]) + rl_[k] * wi[64 + k];
            gsh[tid] = acc;
        }
        __syncthreads();
        if (tid < 64) {
            float ig = gsh[tid], fg = gsh[64 + tid], gg = gsh[128 + tid], og = gsh[192 + tid];
            float cc = cl[tid];
            float si = 1.f / (1.f + __expf(-ig));
            float sf = 1.f / (1.f + __expf(-fg));
            float so = 1.f / (1.f + __expf(-og));
            float cn = sf * cc + si * tanhf(gg);
            cl[tid] = cn;
            hl[tid] = so * tanhf(cn);
        }
        __syncthreads();
        float ev[4];
        int nr = 0;
        float mloc = -1e30f;
        for (int i = tid; i < nrows; i += 256) {
            float d = 0.f;
            if (i < SROWS) {
                const float* rp = &sc[i * 65];
                #pragma unroll 16
                for (int j = 0; j < 64; j++) d += rp[j] * hl[j];
            } else {
                const float* rp = out2 + (size_t)(beg + i) * 64;
                for (int j = 0; j < 64; j++) d += rp[j] * hl[j];
            }
            ev[nr++] = d;
            mloc = fmaxf(mloc, d);
        }
        #pragma unroll
        for (int off = 1; off < 64; off <<= 1) mloc = fmaxf(mloc, __shfl_xor(mloc, off));
        if (lane == 0) red[w] = mloc;
        __syncthreads();
        float m = fmaxf(fmaxf(red[0], red[1]), fmaxf(red[2], red[3]));
        __syncthreads();
        float sloc = 0.f;
        nr = 0;
        for (int i = tid; i < nrows; i += 256) {
            float wv = __expf(ev[nr++] - m);
            if (i < 1024) wlds[i] = wv;
            sloc += wv;
        }
        #pragma unroll
        for (int off = 1; off < 64; off <<= 1) sloc += __shfl_xor(sloc, off);
        if (lane == 0) red[w] = sloc;
        __syncthreads();
        float sv = red[0] + red[1] + red[2] + red[3];
        float inv = sv > 0.f ? 1.f / sv : 0.f;
        float acc = 0.f;
        for (int i = w; i < nrows; i += 4) {
            float v = (i < SROWS) ? sc[i * 65 + lane] : out2[(size_t)(beg + i) * 64 + lane];
            acc += wlds[i] * v;
        }
        gsh[w * 64 + lane] = acc;
        __syncthreads();
        if (tid < 64)
            rl_[tid] = (gsh[tid] + gsh[64 + tid] + gsh[128 + tid] + gsh[192 + tid]) * inv;
        __syncthreads();
    }
    if (tid < 64) {
        float t = b1[tid];
        #pragma unroll 8
        for (int k = 0; k < 64; k++)
            t += hl[k] * W1[(size_t)k * 64 + tid] + rl_[k] * W1[(size_t)(64 + k) * 64 + tid];
        t = fmaxf(t, 0.f) * W2[tid];
        #pragma unroll
        for (int off = 32; off > 0; off >>= 1) t += __shfl_xor(t, off);
        if (tid == 0) out[b] = t + b2[0];
    }
}

// ----------------------------------------------------------------
extern "C" void kernel_launch(void* const* d_in, const int* in_sizes, int n_in,
                              void* d_out, int out_size, void* d_ws, size_t ws_size,
                              hipStream_t stream) {
    const float* x     = (const float*)d_in[0];
    const int*   ei    = (const int*)d_in[1];
    const int*   batch = (const int*)d_in[2];
    const float* W0    = (const float*)d_in[3];
    const float* b0    = (const float*)d_in[4];
    const float* Wg    = (const float*)d_in[5];
    const float* att_s = (const float*)d_in[6];
    const float* att_d = (const float*)d_in[7];
    const float* bg    = (const float*)d_in[8];
    const float* Wh    = (const float*)d_in[9];
    const float* bh    = (const float*)d_in[10];
    const float* W_ih  = (const float*)d_in[11];
    const float* W_hh  = (const float*)d_in[12];
    const float* b_ih  = (const float*)d_in[13];
    const float* b_hh  = (const float*)d_in[14];
    const float* W1    = (const float*)d_in[15];
    const float* b1    = (const float*)d_in[16];
    const float* W2    = (const float*)d_in[17];
    const float* b2    = (const float*)d_in[18];
    float* out = (float*)d_out;

    const int* esrc = ei;
    const int* edst = ei + N_EDGES;

    char* wsb = (char*)d_ws;
    size_t off = 0;
    auto alloc = [&](size_t bytes) {
        void* p = wsb + off;
        off = (off + bytes + 255) & ~(size_t)255;
        return p;
    };
    float* h0      = (float*)alloc((size_t)N_NODES * 64 * 4);
    float* out2    = (float*)alloc((size_t)N_NODES * 64 * 4);
    float* a_s     = (float*)alloc((size_t)N_NODES * 8 * 4);
    float* a_d     = (float*)alloc((size_t)N_NODES * 8 * 4);
    float* vsd     = (float*)alloc(64 * 16 * 4);
    unsigned short* wgt_hi = (unsigned short*)alloc(32768 * 2);
    unsigned short* wgt_lo = (unsigned short*)alloc(32768 * 2);
    unsigned short* wht_hi = (unsigned short*)alloc(32768 * 2);
    unsigned short* wht_lo = (unsigned short*)alloc(32768 * 2);
    int*   deg     = (int*)alloc((size_t)N_NODES * 4);
    int*   tmp     = (int*)alloc((size_t)N_NODES * 4);
    int*   bsum    = (int*)alloc(128 * 4);
    int*   offs    = (int*)alloc((size_t)(N_NODES + 1) * 4);
    int*   cursor  = (int*)alloc((size_t)N_NODES * 4);
    int*   adj     = (int*)alloc((size_t)(N_EDGES + N_NODES) * 4);
    int*   segst   = (int*)alloc((size_t)(NBATCH + 1) * 4);

    const int nscan = (N_NODES + 255) / 256;    // 79
    const int nasd  = N_NODES / 16;             // 1250

    k_small<<<259, 256, 0, stream>>>(Wg, Wh, att_s, att_d, vsd, batch, segst, deg,
                                     wgt_hi, wgt_lo, wht_hi, wht_lo, N_NODES, NBATCH);
    k_h0c<<<N_NODES / 4, 256, 0, stream>>>(x, W0, b0, h0, edst, deg, N_NODES);
    k_asd_scan<<<nasd + nscan, 256, 0, stream>>>(h0, vsd, a_s, a_d, deg, tmp, bsum, nasd, N_NODES);

    k_scan2<<<(N_NODES + 256) / 256, 256, 0, stream>>>(tmp, bsum, offs, adj, cursor, N_NODES, nscan);
    k_fill_edge<<<(N_EDGES + 255) / 256, 256, 0, stream>>>(esrc, edst, cursor, adj, N_EDGES);

    // fused GAT aggregate + MFMA double-GEMM -> out2
    k_gatf<<<N_NODES / 16, 1024, 0, stream>>>(offs, adj, a_s, a_d, h0,
                                              wgt_hi, wgt_lo, wht_hi, wht_lo, bg, bh, out2, N_NODES);

    k_s2s<<<NBATCH, 256, 0, stream>>>(out2, segst, W_ih, W_hh, b_ih, b_hh, W1, b1, W2, b2, out);
}